// Round 5
// baseline (493.940 us; speedup 1.0000x reference)
//
#include <hip/hip_runtime.h>
#include <hip/hip_bf16.h>
#include <cmath>

typedef unsigned short u16;
typedef unsigned int   u32;

using v4f = __attribute__((ext_vector_type(4))) float;
using s8v = __attribute__((ext_vector_type(8))) short;

union Frag { uint4 u; s8v s; };

__device__ __forceinline__ u16 f2bf(float f){
  u32 u = __float_as_uint(f);
  u32 r = u + 0x7fffu + ((u >> 16) & 1u);
  return (u16)(r >> 16);
}
__device__ __forceinline__ float bf2f(u16 h){ return __uint_as_float(((u32)h) << 16); }

// async global->LDS, 16B per lane; LDS dest is wave-uniform base + lane*16
__device__ __forceinline__ void async16(const void* g, void* l){
  __builtin_amdgcn_global_load_lds((__attribute__((address_space(1))) void*)g,
                                   (__attribute__((address_space(3))) void*)l, 16, 0, 0);
}

// ---------------- cast x (fp32 -> bf16) ----------------
__global__ __launch_bounds__(256) void cast_x_kernel(const float* __restrict__ x, u16* __restrict__ xb){
  size_t i = ((size_t)blockIdx.x * 256 + threadIdx.x) * 4;
  float4 v = *(const float4*)(x + i);
  uint2 o;
  o.x = (u32)f2bf(v.x) | ((u32)f2bf(v.y) << 16);
  o.y = (u32)f2bf(v.z) | ((u32)f2bf(v.w) << 16);
  *(uint2*)(xb + i) = o;
}

// ---------------- cast + transpose weights: W[k][n] fp32 -> WT[n][k] bf16 ----------------
__global__ __launch_bounds__(256) void cast_transpose_kernel(
    const float* __restrict__ W0, const float* __restrict__ W1,
    const float* __restrict__ W2, const float* __restrict__ W3,
    u16* __restrict__ T0, u16* __restrict__ T1, u16* __restrict__ T2, u16* __restrict__ T3){
  __shared__ float tile[64][65];
  const float* W = (blockIdx.z==0)?W0:(blockIdx.z==1)?W1:(blockIdx.z==2)?W2:W3;
  u16*         T = (blockIdx.z==0)?T0:(blockIdx.z==1)?T1:(blockIdx.z==2)?T2:T3;
  const int k0 = blockIdx.y*64, n0 = blockIdx.x*64;
  const int t  = threadIdx.x;
  const int rr = t >> 4, c4 = (t & 15) * 4;
  #pragma unroll
  for (int i=0;i<4;i++){
    int k = rr + i*16;
    float4 v = *(const float4*)(W + (size_t)(k0+k)*2048 + n0 + c4);
    tile[k][c4+0]=v.x; tile[k][c4+1]=v.y; tile[k][c4+2]=v.z; tile[k][c4+3]=v.w;
  }
  __syncthreads();
  #pragma unroll
  for (int i=0;i<4;i++){
    int n = rr + i*16;
    uint2 o;
    o.x = (u32)f2bf(tile[c4+0][n]) | ((u32)f2bf(tile[c4+1][n])<<16);
    o.y = (u32)f2bf(tile[c4+2][n]) | ((u32)f2bf(tile[c4+3][n])<<16);
    *(uint2*)(T + (size_t)(n0+n)*2048 + k0 + c4) = o;
  }
}

// ---------------- merged QKV GEMM: [4096][2048] x [6144][2048]^T + bias -> Q/K/V bf16 [B,S,H,D] ----------------
// grid (48, 32); BT rows 0..2047 = Wq^T, 2048..4095 = Wk^T, 4096..6143 = Wv^T (contiguous in ws).
// LDS tiles 128x64 u16, unpadded, 16B-block XOR swizzle (pos = blk ^ (row&7)).
__global__ __launch_bounds__(256) void gemm_qkv_kernel(const u16* __restrict__ A,
                                                       const u16* __restrict__ BTall,
                                                       const float* __restrict__ bq,
                                                       const float* __restrict__ bk,
                                                       const float* __restrict__ bv,
                                                       u16* __restrict__ QKV){
  constexpr int K = 2048;
  __shared__ u16 Asl[128*64];
  __shared__ u16 Bsl[128*64];
  const int tid  = threadIdx.x;
  const int w    = tid >> 6;
  const int lane = tid & 63;
  const int r    = lane & 15, q = lane >> 4;
  const int m0   = blockIdx.y * 128;
  const int n0g  = blockIdx.x * 128;          // 0..6143
  const int sel  = n0g >> 11;                 // 0=q, 1=k, 2=v
  const float* bias = (sel==0)? bq : (sel==1)? bk : bv;
  u16* Cout = QKV + (size_t)sel * 8388608;
  const int wm   = (w >> 1) * 64, wn = (w & 1) * 64;

  v4f acc[4][4];
  #pragma unroll
  for (int i=0;i<4;i++)
    #pragma unroll
    for (int j=0;j<4;j++) acc[i][j] = (v4f)0.f;

  const int srow = w*32 + (lane>>3);
  const int sblk = (lane&7) ^ ((lane>>3)&7);
  const u16* Ag = A     + (size_t)(m0+srow)*K + sblk*8;
  const u16* Bg = BTall + (size_t)(n0g+srow)*K + sblk*8;
  u16* Als = Asl + (w*32)*64;
  u16* Bls = Bsl + (w*32)*64;

  for (int kk = 0; kk < K; kk += 64) {
    #pragma unroll
    for (int i=0;i<4;i++){
      async16(Ag + (size_t)i*8*K + kk, Als + i*512);
      async16(Bg + (size_t)i*8*K + kk, Bls + i*512);
    }
    __syncthreads();
    #pragma unroll
    for (int ks=0; ks<2; ++ks) {
      s8v af[4], bfr[4];
      #pragma unroll
      for (int i=0;i<4;i++){
        int rho = wm + i*16 + r;
        int p = (ks*4 + q) ^ (r&7);
        Frag t; t.u = *(const uint4*)(Asl + rho*64 + p*8); af[i] = t.s;
      }
      #pragma unroll
      for (int j=0;j<4;j++){
        int rho = wn + j*16 + r;
        int p = (ks*4 + q) ^ (r&7);
        Frag t; t.u = *(const uint4*)(Bsl + rho*64 + p*8); bfr[j] = t.s;
      }
      #pragma unroll
      for (int i=0;i<4;i++)
        #pragma unroll
        for (int j=0;j<4;j++)
          acc[i][j] = __builtin_amdgcn_mfma_f32_16x16x32_bf16(af[i], bfr[j], acc[i][j], 0, 0, 0);
    }
    __syncthreads();
  }

  float bvv[4];
  #pragma unroll
  for (int j=0;j<4;j++) bvv[j] = bias[(n0g & 2047) + wn + j*16 + r];

  #pragma unroll
  for (int i=0;i<4;i++){
    #pragma unroll
    for (int j=0;j<4;j++){
      const int gnl = (n0g & 2047) + wn + j*16 + r;   // col within this buffer's E=2048
      #pragma unroll
      for (int rr2=0; rr2<4; ++rr2){
        const int gm = m0 + wm + i*16 + q*4 + rr2;    // token
        Cout[(size_t)gm*2048 + gnl] = f2bf(acc[i][j][rr2] + bvv[j]);
      }
    }
  }
}

// ---------------- bf16 MFMA GEMM (out-proj): C fp32 = A[4096][2048] * BT^T + bias ----------------
__global__ __launch_bounds__(256) void gemm_out_kernel(const u16* __restrict__ A,
                                                       const u16* __restrict__ BT,
                                                       const float* __restrict__ bias,
                                                       float* __restrict__ Cout){
  constexpr int K = 2048;
  __shared__ u16 Asl[128*64];
  __shared__ u16 Bsl[128*64];
  const int tid  = threadIdx.x;
  const int w    = tid >> 6;
  const int lane = tid & 63;
  const int r    = lane & 15, q = lane >> 4;
  const int m0   = blockIdx.y * 128;
  const int n0   = blockIdx.x * 128;
  const int wm   = (w >> 1) * 64, wn = (w & 1) * 64;

  v4f acc[4][4];
  #pragma unroll
  for (int i=0;i<4;i++)
    #pragma unroll
    for (int j=0;j<4;j++) acc[i][j] = (v4f)0.f;

  const int srow = w*32 + (lane>>3);
  const int sblk = (lane&7) ^ ((lane>>3)&7);
  const u16* Ag = A  + (size_t)(m0+srow)*K + sblk*8;
  const u16* Bg = BT + (size_t)(n0+srow)*K + sblk*8;
  u16* Als = Asl + (w*32)*64;
  u16* Bls = Bsl + (w*32)*64;

  for (int kk = 0; kk < K; kk += 64) {
    #pragma unroll
    for (int i=0;i<4;i++){
      async16(Ag + (size_t)i*8*K + kk, Als + i*512);
      async16(Bg + (size_t)i*8*K + kk, Bls + i*512);
    }
    __syncthreads();
    #pragma unroll
    for (int ks=0; ks<2; ++ks) {
      s8v af[4], bfr[4];
      #pragma unroll
      for (int i=0;i<4;i++){
        int rho = wm + i*16 + r;
        int p = (ks*4 + q) ^ (r&7);
        Frag t; t.u = *(const uint4*)(Asl + rho*64 + p*8); af[i] = t.s;
      }
      #pragma unroll
      for (int j=0;j<4;j++){
        int rho = wn + j*16 + r;
        int p = (ks*4 + q) ^ (r&7);
        Frag t; t.u = *(const uint4*)(Bsl + rho*64 + p*8); bfr[j] = t.s;
      }
      #pragma unroll
      for (int i=0;i<4;i++)
        #pragma unroll
        for (int j=0;j<4;j++)
          acc[i][j] = __builtin_amdgcn_mfma_f32_16x16x32_bf16(af[i], bfr[j], acc[i][j], 0, 0, 0);
    }
    __syncthreads();
  }

  float bvv[4];
  #pragma unroll
  for (int j=0;j<4;j++) bvv[j] = bias[n0 + wn + j*16 + r];

  #pragma unroll
  for (int i=0;i<4;i++){
    #pragma unroll
    for (int j=0;j<4;j++){
      const int gn = n0 + wn + j*16 + r;
      #pragma unroll
      for (int rr2=0; rr2<4; ++rr2){
        const int gm = m0 + wm + i*16 + q*4 + rr2;
        Cout[(size_t)gm*2048 + gn] = acc[i][j][rr2] + bvv[j];
      }
    }
  }
}

// ---------------- RoPE in place on bf16 [B,S,H,D], one wave per (b,s,h) row ----------------
__global__ __launch_bounds__(256) void rope_kernel(u16* __restrict__ Q, u16* __restrict__ Kb){
  const int wrow = blockIdx.x*4 + (threadIdx.x >> 6);  // 0 .. 65535 over (b,s,h)
  const int lane = threadIdx.x & 63;
  u16* P = (blockIdx.y == 0) ? Q : Kb;
  const int s = (wrow >> 4) & 2047;
  const size_t base = (size_t)wrow * 128;
  float invf = exp2f(-(float)lane * 0.20762050593045952f);  // log2(10000)/64
  float angle = (float)s * invf;
  float sn, cs;
  sincosf(angle, &sn, &cs);
  float x_j   = bf2f(P[base + lane]);
  float x_j64 = bf2f(P[base + 64 + lane]);
  float x_2j  = bf2f(P[base + 2*lane]);
  float x_2j1 = bf2f(P[base + 2*lane + 1]);
  float o0 = x_j  * cs - x_2j1 * sn;
  float o1 = x_j64 * cs + x_2j  * sn;
  P[base + lane]      = f2bf(o0);
  P[base + 64 + lane] = f2bf(o1);
}

// ---------------- transpose V: [B,S,H,D] -> VT [B,H,D,S] ----------------
__global__ __launch_bounds__(256) void transpose_v_kernel(const u16* __restrict__ V, u16* __restrict__ VT){
  __shared__ u16 t[64*72];
  const int s0 = blockIdx.x*64;
  const int d0 = blockIdx.y*64;
  const int bh = blockIdx.z;
  const int b = bh >> 4, h = bh & 15;
  const size_t obase = ((size_t)bh*128 + d0)*2048 + s0;
  const int tid = threadIdx.x;
  #pragma unroll
  for (int i=0;i<2;i++){
    int c = tid + i*256;
    int sl = c >> 3, dc = (c & 7) * 8;
    *(uint4*)(t + sl*72 + dc) =
      *(const uint4*)(V + ((size_t)(b*2048 + s0 + sl))*2048 + h*128 + d0 + dc);
  }
  __syncthreads();
  #pragma unroll
  for (int i=0;i<2;i++){
    int c = tid + i*256;
    int dl = c >> 3, sc4 = (c & 7) * 8;
    u16 tmp[8];
    #pragma unroll
    for (int j=0;j<8;j++) tmp[j] = t[(sc4+j)*72 + dl];
    *(uint4*)(VT + obase + (size_t)dl*2048 + sc4) = *(const uint4*)tmp;
  }
}

// ---------------- flash attention: Q,K [B,S,H,D], VT [B,H,D,S] -> Out bf16 [B,S,E] ----------------
// Q-tile 128 (wave = 2 x 16 q-rows), K-tile 64. Q-frags loaded DIRECTLY global->regs (16B contiguous).
// LDS 48 KB: K 16K + V 16K + P 16K -> 3 blocks/CU capacity. XOR-swizzled unpadded tiles.
__global__ __launch_bounds__(256,3) void attn_kernel(const u16* __restrict__ Q,
                                                     const u16* __restrict__ K,
                                                     const u16* __restrict__ VT,
                                                     const int* __restrict__ mask,
                                                     u16* __restrict__ Out){
  constexpr int S = 2048;
  constexpr float SL2 = 0.08838834764831845f * 1.4426950408889634f;
  __shared__ u16 smem[24576];
  u16* Klds = smem;            // [64 keys][128 d]
  u16* Vlds = smem + 8192;     // [128 d][64 keys]
  u16* Plds = smem + 16384;    // 4 waves x [32 rows][64 keys]

  const int tid = threadIdx.x, w = tid >> 6, lane = tid & 63;
  const int r = lane & 15, q = lane >> 4;
  const int h = blockIdx.y, b = blockIdx.z;
  const int q0 = blockIdx.x * 128;
  const size_t rowb = (size_t)b * 2048;
  const size_t bhD  = ((size_t)(b*16 + h)) * 128;

  // ---- Q fragments straight from global (A-layout is 16B-contiguous in [B,S,H,D]) ----
  s8v qf[2][4];
  #pragma unroll
  for (int m=0;m<2;m++){
    #pragma unroll
    for (int kc=0;kc<4;kc++){
      Frag t; t.u = *(const uint4*)(Q + (rowb + q0 + w*32 + m*16 + r)*2048 + h*128 + kc*32 + q*8);
      qf[m][kc] = t.s;
    }
  }

  v4f accO[2][8];
  #pragma unroll
  for (int m=0;m<2;m++)
    #pragma unroll
    for (int n=0;n<8;n++) accO[m][n] = (v4f)0.f;
  float lsum[2][4];
  #pragma unroll
  for (int m=0;m<2;m++)
    #pragma unroll
    for (int g=0;g<4;g++) lsum[m][g] = 0.f;

  u16* Pw = Plds + w*2048;     // [32][64]

  const int sr4 = lane >> 4, sp16 = lane & 15;
  const int vr8 = lane >> 3, vblk = (lane&7) ^ ((lane>>3)&7);

  for (int it=0; it<32; ++it){
    const int key0 = it*64;
    // stage K tile [64 keys][128 d]
    #pragma unroll
    for (int i=0;i<4;i++){
      int R = w*16 + i*4;
      int blk = sp16 ^ ((R&7) + sr4);
      async16(K + (rowb + key0 + R + sr4)*2048 + h*128 + blk*8, Klds + R*128);
    }
    // stage VT tile [128 d][64 keys]
    #pragma unroll
    for (int i=0;i<4;i++){
      int R = w*32 + i*8;
      async16(VT + (bhD + R + vr8)*2048 + key0 + vblk*8, Vlds + R*64);
    }
    __syncthreads();

    // ---- S = Q K^T (share kf across both m sub-tiles) ----
    v4f sc[2][4];
    #pragma unroll
    for (int n=0;n<4;n++){
      v4f a0 = (v4f)0.f, a1 = (v4f)0.f;
      #pragma unroll
      for (int kc=0;kc<4;kc++){
        int rho = n*16 + r;
        int p = (kc*4 + q) ^ (r&7);
        Frag t; t.u = *(const uint4*)(Klds + rho*128 + p*8);
        a0 = __builtin_amdgcn_mfma_f32_16x16x32_bf16(qf[0][kc], t.s, a0, 0, 0, 0);
        a1 = __builtin_amdgcn_mfma_f32_16x16x32_bf16(qf[1][kc], t.s, a1, 0, 0, 0);
      }
      sc[0][n] = a0; sc[1][n] = a1;
    }

    int mv[4];
    #pragma unroll
    for (int n=0;n<4;n++) mv[n] = mask[b*S + key0 + n*16 + r];

    // ---- P = exp(score/sqrt(d)) (no-max softmax), lane-partial l ----
    #pragma unroll
    for (int m=0;m<2;m++){
      #pragma unroll
      for (int g=0;g<4;g++){
        const int row = m*16 + q*4 + g;
        const int rb = row*64 + (r&7);
        #pragma unroll
        for (int n=0;n<4;n++){
          float p = exp2f(sc[m][n][g] * SL2);
          if (mv[n] == 0) p = 0.f;
          lsum[m][g] += p;
          int pp = (n*2 + (r>>3)) ^ (row&7);
          Pw[rb + pp*8] = f2bf(p);
        }
      }
    }

    // ---- O += P V ----
    #pragma unroll
    for (int kc=0;kc<2;kc++){
      int p = (kc*4 + q) ^ (r&7);
      s8v pf[2];
      #pragma unroll
      for (int m=0;m<2;m++){
        Frag t; t.u = *(const uint4*)(Pw + (m*16 + r)*64 + p*8);
        pf[m] = t.s;
      }
      #pragma unroll
      for (int n=0;n<8;n++){
        Frag tv; tv.u = *(const uint4*)(Vlds + (n*16 + r)*64 + p*8);
        accO[0][n] = __builtin_amdgcn_mfma_f32_16x16x32_bf16(pf[0], tv.s, accO[0][n], 0, 0, 0);
        accO[1][n] = __builtin_amdgcn_mfma_f32_16x16x32_bf16(pf[1], tv.s, accO[1][n], 0, 0, 0);
      }
    }
    __syncthreads();
  }

  // ---- reduce l across the 16 lanes of each row group ----
  float inv[2][4];
  #pragma unroll
  for (int m=0;m<2;m++){
    #pragma unroll
    for (int g=0;g<4;g++){
      float s = lsum[m][g];
      #pragma unroll
      for (int off=1; off<16; off<<=1) s += __shfl_xor(s, off, 64);
      inv[m][g] = (s > 0.f) ? 1.f/s : 0.f;
    }
  }

  // ---- epilogue: normalize, store bf16 to [B,S,E] ----
  #pragma unroll
  for (int m=0;m<2;m++){
    #pragma unroll
    for (int n=0;n<8;n++){
      #pragma unroll
      for (int g=0;g<4;g++){
        int s = q0 + w*32 + m*16 + q*4 + g;
        int col = h*128 + n*16 + r;
        Out[(rowb + s)*2048 + col] = f2bf(accO[m][n][g] * inv[m][g]);
      }
    }
  }
}

extern "C" void kernel_launch(void* const* d_in, const int* in_sizes, int n_in,
                              void* d_out, int out_size, void* d_ws, size_t ws_size,
                              hipStream_t stream) {
  (void)in_sizes; (void)n_in; (void)out_size; (void)ws_size;
  const float* x    = (const float*)d_in[0];
  const int*   mask = (const int*)d_in[1];
  const float* Wq   = (const float*)d_in[2];
  const float* bq   = (const float*)d_in[3];
  const float* Wk   = (const float*)d_in[4];
  const float* bk   = (const float*)d_in[5];
  const float* Wv   = (const float*)d_in[6];
  const float* bv   = (const float*)d_in[7];
  const float* Wo   = (const float*)d_in[8];
  const float* bo   = (const float*)d_in[9];

  u16* xbf = (u16*)d_ws;                 // 8388608 elems
  u16* WqT = xbf + 8388608;              // 4194304 each; Wq/Wk/Wv contiguous = stacked [6144][2048]
  u16* WkT = WqT + 4194304;
  u16* WvT = WkT + 4194304;
  u16* WoT = WvT + 4194304;
  u16* Qb  = WoT + 4194304;              // 8388608 each, [B,S,H,D] row-major; Qb,Kb,Vb contiguous
  u16* Kb  = Qb + 8388608;
  u16* Vb  = Kb + 8388608;
  u16* Ab  = Vb + 8388608;               // attn out bf16 [B,S,E]
  u16* VTb = Ab + 8388608;               // V transposed [B,H,D,S]

  cast_x_kernel<<<8192, 256, 0, stream>>>(x, xbf);
  cast_transpose_kernel<<<dim3(32,32,4), 256, 0, stream>>>(Wq, Wk, Wv, Wo, WqT, WkT, WvT, WoT);
  gemm_qkv_kernel<<<dim3(48,32), 256, 0, stream>>>(xbf, WqT, bq, bk, bv, Qb);
  rope_kernel<<<dim3(16384,2), 256, 0, stream>>>(Qb, Kb);
  transpose_v_kernel<<<dim3(32,2,32), 256, 0, stream>>>(Vb, VTb);
  attn_kernel<<<dim3(16,16,2), 256, 0, stream>>>(Qb, Kb, VTb, mask, Ab);
  gemm_out_kernel<<<dim3(16,32), 256, 0, stream>>>(Ab, WoT, bo, (float*)d_out);
}